// Round 1
// baseline (4091.187 us; speedup 1.0000x reference)
//
#include <hip/hip_runtime.h>

#define NNODE 16384  // B*N
#define KK 30
#define F 148

#define DECL12 float a00=0,a01=0,a02=0,a10=0,a11=0,a12=0,a20=0,a21=0,a22=0,a30=0,a31=0,a32=0;
#define FMA3x4(v0_,v1_,v2_,w_) \
  a00=fmaf(v0_,w_.x,a00); a01=fmaf(v1_,w_.x,a01); a02=fmaf(v2_,w_.x,a02); \
  a10=fmaf(v0_,w_.y,a10); a11=fmaf(v1_,w_.y,a11); a12=fmaf(v2_,w_.y,a12); \
  a20=fmaf(v0_,w_.z,a20); a21=fmaf(v1_,w_.z,a21); a22=fmaf(v2_,w_.z,a22); \
  a30=fmaf(v0_,w_.w,a30); a31=fmaf(v1_,w_.w,a31); a32=fmaf(v2_,w_.w,a32);

__global__ __launch_bounds__(256, 2)
void mpnn_fused(const float* __restrict__ h_V, const float* __restrict__ h_M,
                const int* __restrict__ mask_V, const int* __restrict__ mask_attend,
                const float* __restrict__ Wh1, const float* __restrict__ Wv1,
                const float* __restrict__ Ws1, const float* __restrict__ bs1,
                const float* __restrict__ Wh2, const float* __restrict__ Wv2,
                const float* __restrict__ Ws2, const float* __restrict__ bs2,
                const float* __restrict__ Wh3, const float* __restrict__ Wv3,
                const float* __restrict__ Ws3, const float* __restrict__ bs3,
                const float* __restrict__ Wh4, const float* __restrict__ Wv4,
                const float* __restrict__ Ws4, const float* __restrict__ bs4,
                const float* __restrict__ Wh5, const float* __restrict__ Wv5,
                const float* __restrict__ Ws5, const float* __restrict__ bs5,
                const float* __restrict__ ln0_g, const float* __restrict__ ln0_b,
                const float* __restrict__ ln1_g, const float* __restrict__ ln1_b,
                float* __restrict__ out)
{
  __shared__ __align__(16) float sv[F];
  __shared__ __align__(16) float dh[F];
  __shared__ __align__(16) float sA[KK][232];   // s_cat(200)+vn1(32); later s2+vn3; node scratch
  __shared__ __align__(16) float sB[KK][116];   // s1+vn2; later s3
  __shared__ __align__(16) float vA[KK][33][3]; // v_cat(32); later v1, v2, v3 (padded stride)
  __shared__ __align__(16) float vB[KK][33][3]; // vh buffers
  __shared__ __align__(16) float wWh1[1024];
  __shared__ __align__(16) float wWv1[512];
  __shared__ __align__(16) float wWh2[256];
  __shared__ __align__(16) float wWv2[256];
  __shared__ __align__(16) float wWh3[256];
  __shared__ __align__(16) float wWv3[256];
  __shared__ float mka[KK];

  const int tid = threadIdx.x;
  const int node = blockIdx.x;

  // ---------------- load node feats, small weights, edge feats ----------------
  for (int f = tid; f < F; f += 256) { sv[f] = h_V[node * F + f]; dh[f] = 0.f; }
  for (int i = tid; i < 1024; i += 256) wWh1[i] = Wh1[i];
  for (int i = tid; i < 512; i += 256) wWv1[i] = Wv1[i];
  if (tid < 256) { wWh2[tid] = Wh2[tid]; wWv2[tid] = Wv2[tid];
                   wWh3[tid] = Wh3[tid]; wWv3[tid] = Wv3[tid]; }
  if (tid < KK) mka[tid] = (float)mask_attend[node * KK + tid];
  for (int task = tid; task < KK * 37; task += 256) {
    int k = task / 37, q = task % 37;
    float4 d = *(const float4*)(h_M + ((long)node * KK + k) * F + q * 4);
    float vals[4] = {d.x, d.y, d.z, d.w};
#pragma unroll
    for (int u = 0; u < 4; u++) {
      int f = q * 4 + u;
      if (f < 48) vA[k][16 + f / 3][f % 3] = vals[u];
      else        sA[k][100 + f - 48]      = vals[u];
    }
  }
  __syncthreads();
  // node part of v_cat / s_cat (needs sv in LDS)
  for (int task = tid; task < KK * 48; task += 256) {
    int k = task / 48, f = task % 48;
    vA[k][f / 3][f % 3] = sv[f];
  }
  for (int task = tid; task < KK * 100; task += 256) {
    int k = task / 100, j = task % 100;
    sA[k][j] = sv[48 + j];
  }
  __syncthreads();

  // ---------------- GVP1: vh (32 in -> 32 out), vn -> sA[.][200+h] ----------------
  for (int task = tid; task < KK * 8; task += 256) {
    int k = task >> 3, h0 = (task & 7) * 4;
    DECL12
#pragma unroll 4
    for (int i = 0; i < 32; i++) {
      float v0 = vA[k][i][0], v1 = vA[k][i][1], v2 = vA[k][i][2];
      float4 w = *(const float4*)&wWh1[i * 32 + h0];
      FMA3x4(v0, v1, v2, w)
    }
    vB[k][h0+0][0]=a00; vB[k][h0+0][1]=a01; vB[k][h0+0][2]=a02;
    vB[k][h0+1][0]=a10; vB[k][h0+1][1]=a11; vB[k][h0+1][2]=a12;
    vB[k][h0+2][0]=a20; vB[k][h0+2][1]=a21; vB[k][h0+2][2]=a22;
    vB[k][h0+3][0]=a30; vB[k][h0+3][1]=a31; vB[k][h0+3][2]=a32;
    sA[k][200+h0+0] = sqrtf(a00*a00+a01*a01+a02*a02 + 1e-8f);
    sA[k][200+h0+1] = sqrtf(a10*a10+a11*a11+a12*a12 + 1e-8f);
    sA[k][200+h0+2] = sqrtf(a20*a20+a21*a21+a22*a22 + 1e-8f);
    sA[k][200+h0+3] = sqrtf(a30*a30+a31*a31+a32*a32 + 1e-8f);
  }
  __syncthreads();
  // s_out1 = relu([s|vn] @ Ws1 + bs1)  -> sB[k][0..99]
  for (int task = tid; task < KK * 25; task += 256) {
    int k = task / 25, j0 = (task % 25) * 4;
    float4 acc = *(const float4*)(bs1 + j0);
    const float* w = Ws1 + j0;
#pragma unroll 4
    for (int i = 0; i < 232; i++) {
      float s = sA[k][i];
      float4 w4 = *(const float4*)(w + i * 100);
      acc.x = fmaf(s, w4.x, acc.x); acc.y = fmaf(s, w4.y, acc.y);
      acc.z = fmaf(s, w4.z, acc.z); acc.w = fmaf(s, w4.w, acc.w);
    }
    acc.x = fmaxf(acc.x, 0.f); acc.y = fmaxf(acc.y, 0.f);
    acc.z = fmaxf(acc.z, 0.f); acc.w = fmaxf(acc.w, 0.f);
    *(float4*)&sB[k][j0] = acc;
  }
  // v_out1 = gate(vh @ Wv1) -> vA[k][0..15]
  for (int task = tid; task < KK * 4; task += 256) {
    int k = task >> 2, o0 = (task & 3) * 4;
    DECL12
#pragma unroll 4
    for (int h = 0; h < 32; h++) {
      float v0 = vB[k][h][0], v1 = vB[k][h][1], v2 = vB[k][h][2];
      float4 w = *(const float4*)&wWv1[h * 16 + o0];
      FMA3x4(v0, v1, v2, w)
    }
    {
      float vn = sqrtf(a00*a00+a01*a01+a02*a02 + 1e-8f);
      float g = 1.f / (1.f + expf(-vn));
      vA[k][o0+0][0]=a00*g; vA[k][o0+0][1]=a01*g; vA[k][o0+0][2]=a02*g;
      vn = sqrtf(a10*a10+a11*a11+a12*a12 + 1e-8f);
      g = 1.f / (1.f + expf(-vn));
      vA[k][o0+1][0]=a10*g; vA[k][o0+1][1]=a11*g; vA[k][o0+1][2]=a12*g;
      vn = sqrtf(a20*a20+a21*a21+a22*a22 + 1e-8f);
      g = 1.f / (1.f + expf(-vn));
      vA[k][o0+2][0]=a20*g; vA[k][o0+2][1]=a21*g; vA[k][o0+2][2]=a22*g;
      vn = sqrtf(a30*a30+a31*a31+a32*a32 + 1e-8f);
      g = 1.f / (1.f + expf(-vn));
      vA[k][o0+3][0]=a30*g; vA[k][o0+3][1]=a31*g; vA[k][o0+3][2]=a32*g;
    }
  }
  __syncthreads();

  // ---------------- GVP2: vh2 (16->16), vn2 -> sB[.][100+h] ----------------
  for (int task = tid; task < KK * 4; task += 256) {
    int k = task >> 2, h0 = (task & 3) * 4;
    DECL12
#pragma unroll 4
    for (int i = 0; i < 16; i++) {
      float v0 = vA[k][i][0], v1 = vA[k][i][1], v2 = vA[k][i][2];
      float4 w = *(const float4*)&wWh2[i * 16 + h0];
      FMA3x4(v0, v1, v2, w)
    }
    vB[k][h0+0][0]=a00; vB[k][h0+0][1]=a01; vB[k][h0+0][2]=a02;
    vB[k][h0+1][0]=a10; vB[k][h0+1][1]=a11; vB[k][h0+1][2]=a12;
    vB[k][h0+2][0]=a20; vB[k][h0+2][1]=a21; vB[k][h0+2][2]=a22;
    vB[k][h0+3][0]=a30; vB[k][h0+3][1]=a31; vB[k][h0+3][2]=a32;
    sB[k][100+h0+0] = sqrtf(a00*a00+a01*a01+a02*a02 + 1e-8f);
    sB[k][100+h0+1] = sqrtf(a10*a10+a11*a11+a12*a12 + 1e-8f);
    sB[k][100+h0+2] = sqrtf(a20*a20+a21*a21+a22*a22 + 1e-8f);
    sB[k][100+h0+3] = sqrtf(a30*a30+a31*a31+a32*a32 + 1e-8f);
  }
  __syncthreads();
  // s_out2 -> sA[k][0..99] (relu)
  for (int task = tid; task < KK * 25; task += 256) {
    int k = task / 25, j0 = (task % 25) * 4;
    float4 acc = *(const float4*)(bs2 + j0);
    const float* w = Ws2 + j0;
#pragma unroll 4
    for (int i = 0; i < 116; i++) {
      float s = sB[k][i];
      float4 w4 = *(const float4*)(w + i * 100);
      acc.x = fmaf(s, w4.x, acc.x); acc.y = fmaf(s, w4.y, acc.y);
      acc.z = fmaf(s, w4.z, acc.z); acc.w = fmaf(s, w4.w, acc.w);
    }
    acc.x = fmaxf(acc.x, 0.f); acc.y = fmaxf(acc.y, 0.f);
    acc.z = fmaxf(acc.z, 0.f); acc.w = fmaxf(acc.w, 0.f);
    *(float4*)&sA[k][j0] = acc;
  }
  // v_out2 (gated) -> vA[k][0..15]
  for (int task = tid; task < KK * 4; task += 256) {
    int k = task >> 2, o0 = (task & 3) * 4;
    DECL12
#pragma unroll 4
    for (int h = 0; h < 16; h++) {
      float v0 = vB[k][h][0], v1 = vB[k][h][1], v2 = vB[k][h][2];
      float4 w = *(const float4*)&wWv2[h * 16 + o0];
      FMA3x4(v0, v1, v2, w)
    }
    {
      float vn = sqrtf(a00*a00+a01*a01+a02*a02 + 1e-8f);
      float g = 1.f / (1.f + expf(-vn));
      vA[k][o0+0][0]=a00*g; vA[k][o0+0][1]=a01*g; vA[k][o0+0][2]=a02*g;
      vn = sqrtf(a10*a10+a11*a11+a12*a12 + 1e-8f);
      g = 1.f / (1.f + expf(-vn));
      vA[k][o0+1][0]=a10*g; vA[k][o0+1][1]=a11*g; vA[k][o0+1][2]=a12*g;
      vn = sqrtf(a20*a20+a21*a21+a22*a22 + 1e-8f);
      g = 1.f / (1.f + expf(-vn));
      vA[k][o0+2][0]=a20*g; vA[k][o0+2][1]=a21*g; vA[k][o0+2][2]=a22*g;
      vn = sqrtf(a30*a30+a31*a31+a32*a32 + 1e-8f);
      g = 1.f / (1.f + expf(-vn));
      vA[k][o0+3][0]=a30*g; vA[k][o0+3][1]=a31*g; vA[k][o0+3][2]=a32*g;
    }
  }
  __syncthreads();

  // ---------------- GVP3: vh3, vn3 -> sA[.][100+h] ----------------
  for (int task = tid; task < KK * 4; task += 256) {
    int k = task >> 2, h0 = (task & 3) * 4;
    DECL12
#pragma unroll 4
    for (int i = 0; i < 16; i++) {
      float v0 = vA[k][i][0], v1 = vA[k][i][1], v2 = vA[k][i][2];
      float4 w = *(const float4*)&wWh3[i * 16 + h0];
      FMA3x4(v0, v1, v2, w)
    }
    vB[k][h0+0][0]=a00; vB[k][h0+0][1]=a01; vB[k][h0+0][2]=a02;
    vB[k][h0+1][0]=a10; vB[k][h0+1][1]=a11; vB[k][h0+1][2]=a12;
    vB[k][h0+2][0]=a20; vB[k][h0+2][1]=a21; vB[k][h0+2][2]=a22;
    vB[k][h0+3][0]=a30; vB[k][h0+3][1]=a31; vB[k][h0+3][2]=a32;
    sA[k][100+h0+0] = sqrtf(a00*a00+a01*a01+a02*a02 + 1e-8f);
    sA[k][100+h0+1] = sqrtf(a10*a10+a11*a11+a12*a12 + 1e-8f);
    sA[k][100+h0+2] = sqrtf(a20*a20+a21*a21+a22*a22 + 1e-8f);
    sA[k][100+h0+3] = sqrtf(a30*a30+a31*a31+a32*a32 + 1e-8f);
  }
  __syncthreads();
  // s_out3 (no relu) -> sB[k][0..99]
  for (int task = tid; task < KK * 25; task += 256) {
    int k = task / 25, j0 = (task % 25) * 4;
    float4 acc = *(const float4*)(bs3 + j0);
    const float* w = Ws3 + j0;
#pragma unroll 4
    for (int i = 0; i < 116; i++) {
      float s = sA[k][i];
      float4 w4 = *(const float4*)(w + i * 100);
      acc.x = fmaf(s, w4.x, acc.x); acc.y = fmaf(s, w4.y, acc.y);
      acc.z = fmaf(s, w4.z, acc.z); acc.w = fmaf(s, w4.w, acc.w);
    }
    *(float4*)&sB[k][j0] = acc;
  }
  // v_out3 (no gate) -> vA[k][0..15]
  for (int task = tid; task < KK * 4; task += 256) {
    int k = task >> 2, o0 = (task & 3) * 4;
    DECL12
#pragma unroll 4
    for (int h = 0; h < 16; h++) {
      float v0 = vB[k][h][0], v1 = vB[k][h][1], v2 = vB[k][h][2];
      float4 w = *(const float4*)&wWv3[h * 16 + o0];
      FMA3x4(v0, v1, v2, w)
    }
    vA[k][o0+0][0]=a00; vA[k][o0+0][1]=a01; vA[k][o0+0][2]=a02;
    vA[k][o0+1][0]=a10; vA[k][o0+1][1]=a11; vA[k][o0+1][2]=a12;
    vA[k][o0+2][0]=a20; vA[k][o0+2][1]=a21; vA[k][o0+2][2]=a22;
    vA[k][o0+3][0]=a30; vA[k][o0+3][1]=a31; vA[k][o0+3][2]=a32;
  }
  __syncthreads();

  // ---------------- masked mean over K -> dh ----------------
  for (int f = tid; f < F; f += 256) {
    float acc = 0.f;
    for (int k = 0; k < KK; k++) {
      float val = (f < 48) ? vA[k][f / 3][f % 3] : sB[k][f - 48];
      acc += mka[k] * val;
    }
    dh[f] = acc * (1.f / (float)KK);
  }
  __syncthreads();

  // ---------------- node phase (reuse sA as scratch) ----------------
  float* ns   = &sA[0][0];
  float* xb   = ns;          // 148
  float* hb   = ns + 160;    // 148
  float* nvh4 = ns + 320;    // 96
  float* nvn4 = ns + 416;    // 32
  float* s4   = ns + 448;    // 400 (+32 vn5 at 848 -> contiguous 432)
  float* nvn5 = ns + 848;    // 32
  float* v4   = ns + 880;    // 96
  float* nvh5 = ns + 976;    // 96
  float* v5   = ns + 1072;   // 48
  float* s5   = ns + 1120;   // 100
  float* red  = ns + 1220;   // 8
  float* part = ns + 1232;   // 400

  for (int f = tid; f < F; f += 256) xb[f] = sv[f] + dh[f];
  __syncthreads();
  // ln0 stats
  if (tid == 0) {
    float s = 0.f;
    for (int i = 0; i < 16; i++) {
      float x0 = xb[3*i], x1 = xb[3*i+1], x2 = xb[3*i+2];
      s += x0*x0 + x1*x1 + x2*x2;
    }
    red[0] = sqrtf(s * (1.f/16.f) + 1e-8f);
  }
  if (tid == 64)  { float s = 0.f; for (int j = 0; j < 100; j++) s += xb[48+j]; red[1] = s * 0.01f; }
  if (tid == 128) { float s = 0.f; for (int j = 0; j < 100; j++) { float v = xb[48+j]; s += v*v; } red[2] = s * 0.01f; }
  __syncthreads();
  {
    float denom = red[0], mu = red[1];
    float var = red[2] - mu * mu;
    float rs = rsqrtf(var + 1e-5f);
    for (int f = tid; f < F; f += 256) {
      if (f < 48) hb[f] = xb[f] / denom;
      else { int j = f - 48; hb[f] = (xb[f] - mu) * rs * ln0_g[j] + ln0_b[j]; }
    }
  }
  __syncthreads();

  // GVP4: vh4 (16 -> 32)
  for (int task = tid; task < 8; task += 256) {
    int h0 = task * 4;
    DECL12
#pragma unroll 4
    for (int i = 0; i < 16; i++) {
      float v0 = hb[3*i], v1 = hb[3*i+1], v2 = hb[3*i+2];
      float4 w = *(const float4*)(Wh4 + i * 32 + h0);
      FMA3x4(v0, v1, v2, w)
    }
    nvh4[3*(h0+0)+0]=a00; nvh4[3*(h0+0)+1]=a01; nvh4[3*(h0+0)+2]=a02;
    nvh4[3*(h0+1)+0]=a10; nvh4[3*(h0+1)+1]=a11; nvh4[3*(h0+1)+2]=a12;
    nvh4[3*(h0+2)+0]=a20; nvh4[3*(h0+2)+1]=a21; nvh4[3*(h0+2)+2]=a22;
    nvh4[3*(h0+3)+0]=a30; nvh4[3*(h0+3)+1]=a31; nvh4[3*(h0+3)+2]=a32;
    nvn4[h0+0] = sqrtf(a00*a00+a01*a01+a02*a02 + 1e-8f);
    nvn4[h0+1] = sqrtf(a10*a10+a11*a11+a12*a12 + 1e-8f);
    nvn4[h0+2] = sqrtf(a20*a20+a21*a21+a22*a22 + 1e-8f);
    nvn4[h0+3] = sqrtf(a30*a30+a31*a31+a32*a32 + 1e-8f);
  }
  __syncthreads();
  // s_out4: 400 outputs, dot 132 (relu)
  for (int task = tid; task < 100; task += 256) {
    int j0 = task * 4;
    float4 acc = *(const float4*)(bs4 + j0);
    const float* w = Ws4 + j0;
#pragma unroll 4
    for (int i = 0; i < 100; i++) {
      float s = hb[48 + i];
      float4 w4 = *(const float4*)(w + i * 400);
      acc.x = fmaf(s, w4.x, acc.x); acc.y = fmaf(s, w4.y, acc.y);
      acc.z = fmaf(s, w4.z, acc.z); acc.w = fmaf(s, w4.w, acc.w);
    }
#pragma unroll 4
    for (int h = 0; h < 32; h++) {
      float s = nvn4[h];
      float4 w4 = *(const float4*)(w + (100 + h) * 400);
      acc.x = fmaf(s, w4.x, acc.x); acc.y = fmaf(s, w4.y, acc.y);
      acc.z = fmaf(s, w4.z, acc.z); acc.w = fmaf(s, w4.w, acc.w);
    }
    acc.x = fmaxf(acc.x, 0.f); acc.y = fmaxf(acc.y, 0.f);
    acc.z = fmaxf(acc.z, 0.f); acc.w = fmaxf(acc.w, 0.f);
    *(float4*)&s4[j0] = acc;
  }
  // v_out4 (gated): 32 outputs from vh4(32)
  for (int task = tid; task < 8; task += 256) {
    int o0 = task * 4;
    DECL12
#pragma unroll 4
    for (int h = 0; h < 32; h++) {
      float v0 = nvh4[3*h], v1 = nvh4[3*h+1], v2 = nvh4[3*h+2];
      float4 w = *(const float4*)(Wv4 + h * 32 + o0);
      FMA3x4(v0, v1, v2, w)
    }
    {
      float vn = sqrtf(a00*a00+a01*a01+a02*a02 + 1e-8f);
      float g = 1.f / (1.f + expf(-vn));
      v4[3*(o0+0)+0]=a00*g; v4[3*(o0+0)+1]=a01*g; v4[3*(o0+0)+2]=a02*g;
      vn = sqrtf(a10*a10+a11*a11+a12*a12 + 1e-8f); g = 1.f / (1.f + expf(-vn));
      v4[3*(o0+1)+0]=a10*g; v4[3*(o0+1)+1]=a11*g; v4[3*(o0+1)+2]=a12*g;
      vn = sqrtf(a20*a20+a21*a21+a22*a22 + 1e-8f); g = 1.f / (1.f + expf(-vn));
      v4[3*(o0+2)+0]=a20*g; v4[3*(o0+2)+1]=a21*g; v4[3*(o0+2)+2]=a22*g;
      vn = sqrtf(a30*a30+a31*a31+a32*a32 + 1e-8f); g = 1.f / (1.f + expf(-vn));
      v4[3*(o0+3)+0]=a30*g; v4[3*(o0+3)+1]=a31*g; v4[3*(o0+3)+2]=a32*g;
    }
  }
  __syncthreads();
  // GVP5: vh5 (32 -> 32), vn5 contiguous after s4
  for (int task = tid; task < 8; task += 256) {
    int h0 = task * 4;
    DECL12
#pragma unroll 4
    for (int i = 0; i < 32; i++) {
      float v0 = v4[3*i], v1 = v4[3*i+1], v2 = v4[3*i+2];
      float4 w = *(const float4*)(Wh5 + i * 32 + h0);
      FMA3x4(v0, v1, v2, w)
    }
    nvh5[3*(h0+0)+0]=a00; nvh5[3*(h0+0)+1]=a01; nvh5[3*(h0+0)+2]=a02;
    nvh5[3*(h0+1)+0]=a10; nvh5[3*(h0+1)+1]=a11; nvh5[3*(h0+1)+2]=a12;
    nvh5[3*(h0+2)+0]=a20; nvh5[3*(h0+2)+1]=a21; nvh5[3*(h0+2)+2]=a22;
    nvh5[3*(h0+3)+0]=a30; nvh5[3*(h0+3)+1]=a31; nvh5[3*(h0+3)+2]=a32;
    nvn5[h0+0] = sqrtf(a00*a00+a01*a01+a02*a02 + 1e-8f);
    nvn5[h0+1] = sqrtf(a10*a10+a11*a11+a12*a12 + 1e-8f);
    nvn5[h0+2] = sqrtf(a20*a20+a21*a21+a22*a22 + 1e-8f);
    nvn5[h0+3] = sqrtf(a30*a30+a31*a31+a32*a32 + 1e-8f);
  }
  __syncthreads();
  // s_out5: 100 outputs, dot 432 (no relu), K split 4 ways
  for (int task = tid; task < 100; task += 256) {
    int jq = task / 4, c = task % 4, j0 = jq * 4;
    int ibeg = c * 108, iend = ibeg + 108;
    float4 acc = make_float4(0.f, 0.f, 0.f, 0.f);
    const float* w = Ws5 + j0;
#pragma unroll 4
    for (int i = ibeg; i < iend; i++) {
      float s = s4[i];  // s4[0..399] then nvn5[0..31], contiguous
      float4 w4 = *(const float4*)(w + i * 100);
      acc.x = fmaf(s, w4.x, acc.x); acc.y = fmaf(s, w4.y, acc.y);
      acc.z = fmaf(s, w4.z, acc.z); acc.w = fmaf(s, w4.w, acc.w);
    }
    *(float4*)&part[task * 4] = acc;
  }
  // v_out5 (no gate): 16 outputs from vh5(32)
  for (int task = tid; task < 4; task += 256) {
    int o0 = task * 4;
    DECL12
#pragma unroll 4
    for (int h = 0; h < 32; h++) {
      float v0 = nvh5[3*h], v1 = nvh5[3*h+1], v2 = nvh5[3*h+2];
      float4 w = *(const float4*)(Wv5 + h * 16 + o0);
      FMA3x4(v0, v1, v2, w)
    }
    v5[3*(o0+0)+0]=a00; v5[3*(o0+0)+1]=a01; v5[3*(o0+0)+2]=a02;
    v5[3*(o0+1)+0]=a10; v5[3*(o0+1)+1]=a11; v5[3*(o0+1)+2]=a12;
    v5[3*(o0+2)+0]=a20; v5[3*(o0+2)+1]=a21; v5[3*(o0+2)+2]=a22;
    v5[3*(o0+3)+0]=a30; v5[3*(o0+3)+1]=a31; v5[3*(o0+3)+2]=a32;
  }
  __syncthreads();
  // reduce s_out5 partials + bias
  for (int task = tid; task < 25; task += 256) {
    int j0 = task * 4;
    float4 p0 = *(const float4*)&part[(task*4+0)*4];
    float4 p1 = *(const float4*)&part[(task*4+1)*4];
    float4 p2 = *(const float4*)&part[(task*4+2)*4];
    float4 p3 = *(const float4*)&part[(task*4+3)*4];
    float4 b = *(const float4*)(bs5 + j0);
    s5[j0+0] = b.x + p0.x + p1.x + p2.x + p3.x;
    s5[j0+1] = b.y + p0.y + p1.y + p2.y + p3.y;
    s5[j0+2] = b.z + p0.z + p1.z + p2.z + p3.z;
    s5[j0+3] = b.w + p0.w + p1.w + p2.w + p3.w;
  }
  __syncthreads();
  // x2 = h + dh2
  for (int f = tid; f < F; f += 256) {
    float d = (f < 48) ? v5[f] : s5[f - 48];
    xb[f] = hb[f] + d;
  }
  __syncthreads();
  // ln1 stats
  if (tid == 0) {
    float s = 0.f;
    for (int i = 0; i < 16; i++) {
      float x0 = xb[3*i], x1 = xb[3*i+1], x2 = xb[3*i+2];
      s += x0*x0 + x1*x1 + x2*x2;
    }
    red[0] = sqrtf(s * (1.f/16.f) + 1e-8f);
  }
  if (tid == 64)  { float s = 0.f; for (int j = 0; j < 100; j++) s += xb[48+j]; red[1] = s * 0.01f; }
  if (tid == 128) { float s = 0.f; for (int j = 0; j < 100; j++) { float v = xb[48+j]; s += v*v; } red[2] = s * 0.01f; }
  __syncthreads();
  {
    float denom = red[0], mu = red[1];
    float var = red[2] - mu * mu;
    float rs = rsqrtf(var + 1e-5f);
    float mv = (float)mask_V[node];
    for (int f = tid; f < F; f += 256) {
      float val;
      if (f < 48) val = xb[f] / denom;
      else { int j = f - 48; val = (xb[f] - mu) * rs * ln1_g[j] + ln1_b[j]; }
      out[node * F + f] = mv * val;
    }
  }
}

extern "C" void kernel_launch(void* const* d_in, const int* in_sizes, int n_in,
                              void* d_out, int out_size, void* d_ws, size_t ws_size,
                              hipStream_t stream) {
  const float* h_V  = (const float*)d_in[0];
  const float* h_M  = (const float*)d_in[1];
  const int* mask_V = (const int*)d_in[2];
  const int* mask_attend = (const int*)d_in[3];
  const float* Wh1 = (const float*)d_in[4];
  const float* Wv1 = (const float*)d_in[5];
  const float* Ws1 = (const float*)d_in[6];
  const float* bs1 = (const float*)d_in[7];
  const float* Wh2 = (const float*)d_in[8];
  const float* Wv2 = (const float*)d_in[9];
  const float* Ws2 = (const float*)d_in[10];
  const float* bs2 = (const float*)d_in[11];
  const float* Wh3 = (const float*)d_in[12];
  const float* Wv3 = (const float*)d_in[13];
  const float* Ws3 = (const float*)d_in[14];
  const float* bs3 = (const float*)d_in[15];
  const float* Wh4 = (const float*)d_in[16];
  const float* Wv4 = (const float*)d_in[17];
  const float* Ws4 = (const float*)d_in[18];
  const float* bs4 = (const float*)d_in[19];
  const float* Wh5 = (const float*)d_in[20];
  const float* Wv5 = (const float*)d_in[21];
  const float* Ws5 = (const float*)d_in[22];
  const float* bs5 = (const float*)d_in[23];
  const float* ln0_g = (const float*)d_in[24];
  const float* ln0_b = (const float*)d_in[25];
  const float* ln1_g = (const float*)d_in[26];
  const float* ln1_b = (const float*)d_in[27];
  float* out = (float*)d_out;

  mpnn_fused<<<dim3(NNODE), dim3(256), 0, stream>>>(
      h_V, h_M, mask_V, mask_attend,
      Wh1, Wv1, Ws1, bs1, Wh2, Wv2, Ws2, bs2, Wh3, Wv3, Ws3, bs3,
      Wh4, Wv4, Ws4, bs4, Wh5, Wv5, Ws5, bs5,
      ln0_g, ln0_b, ln1_g, ln1_b, out);
}

// Round 2
// 1644.179 us; speedup vs baseline: 2.4883x; 2.4883x over previous
//
#include <hip/hip_runtime.h>

#define KK 30
#define F 148
#define NNODE 16384

#define DECL12 float a00=0,a01=0,a02=0,a10=0,a11=0,a12=0,a20=0,a21=0,a22=0,a30=0,a31=0,a32=0;
#define FMA3x4(v0_,v1_,v2_,w_) \
  a00=fmaf(v0_,w_.x,a00); a01=fmaf(v1_,w_.x,a01); a02=fmaf(v2_,w_.x,a02); \
  a10=fmaf(v0_,w_.y,a10); a11=fmaf(v1_,w_.y,a11); a12=fmaf(v2_,w_.y,a12); \
  a20=fmaf(v0_,w_.z,a20); a21=fmaf(v1_,w_.z,a21); a22=fmaf(v2_,w_.z,a22); \
  a30=fmaf(v0_,w_.w,a30); a31=fmaf(v1_,w_.w,a31); a32=fmaf(v2_,w_.w,a32);

#define SDOT4(ACC, SPTR) { float4 s_ = *(const float4*)(SPTR); \
  ACC.x=fmaf(s_.x,w0.x,ACC.x); ACC.y=fmaf(s_.x,w0.y,ACC.y); ACC.z=fmaf(s_.x,w0.z,ACC.z); ACC.w=fmaf(s_.x,w0.w,ACC.w); \
  ACC.x=fmaf(s_.y,w1.x,ACC.x); ACC.y=fmaf(s_.y,w1.y,ACC.y); ACC.z=fmaf(s_.y,w1.z,ACC.z); ACC.w=fmaf(s_.y,w1.w,ACC.w); \
  ACC.x=fmaf(s_.z,w2.x,ACC.x); ACC.y=fmaf(s_.z,w2.y,ACC.y); ACC.z=fmaf(s_.z,w2.z,ACC.z); ACC.w=fmaf(s_.z,w2.w,ACC.w); \
  ACC.x=fmaf(s_.w,w3.x,ACC.x); ACC.y=fmaf(s_.w,w3.y,ACC.y); ACC.z=fmaf(s_.w,w3.z,ACC.z); ACC.w=fmaf(s_.w,w3.w,ACC.w); }

#define GATE3(x0,x1,x2,d0,d1,d2) { float vn_=sqrtf((x0)*(x0)+(x1)*(x1)+(x2)*(x2)+1e-8f); \
  float g_=1.f/(1.f+expf(-vn_)); d0=(x0)*g_; d1=(x1)*g_; d2=(x2)*g_; }

// k-tiled scalar-path matvec: 6 edges share one weight stream.
template<bool RELU>
__device__ __forceinline__ void stask6(const float* __restrict__ w, float4 binit, int niter,
                                       const float* s0p, const float* s1p, const float* s2p,
                                       const float* s3p, const float* s4p, const float* s5p,
                                       float* d0, float* d1, float* d2, float* d3, float* d4, float* d5)
{
  float4 a0 = binit, a1 = binit, a2 = binit, a3 = binit, a4 = binit, a5 = binit;
#pragma unroll 2
  for (int i0 = 0; i0 < niter; i0 += 4) {
    float4 w0 = *(const float4*)(w + (i0 + 0) * 100);
    float4 w1 = *(const float4*)(w + (i0 + 1) * 100);
    float4 w2 = *(const float4*)(w + (i0 + 2) * 100);
    float4 w3 = *(const float4*)(w + (i0 + 3) * 100);
    SDOT4(a0, s0p + i0) SDOT4(a1, s1p + i0) SDOT4(a2, s2p + i0)
    SDOT4(a3, s3p + i0) SDOT4(a4, s4p + i0) SDOT4(a5, s5p + i0)
  }
  if (RELU) {
    a0.x=fmaxf(a0.x,0.f); a0.y=fmaxf(a0.y,0.f); a0.z=fmaxf(a0.z,0.f); a0.w=fmaxf(a0.w,0.f);
    a1.x=fmaxf(a1.x,0.f); a1.y=fmaxf(a1.y,0.f); a1.z=fmaxf(a1.z,0.f); a1.w=fmaxf(a1.w,0.f);
    a2.x=fmaxf(a2.x,0.f); a2.y=fmaxf(a2.y,0.f); a2.z=fmaxf(a2.z,0.f); a2.w=fmaxf(a2.w,0.f);
    a3.x=fmaxf(a3.x,0.f); a3.y=fmaxf(a3.y,0.f); a3.z=fmaxf(a3.z,0.f); a3.w=fmaxf(a3.w,0.f);
    a4.x=fmaxf(a4.x,0.f); a4.y=fmaxf(a4.y,0.f); a4.z=fmaxf(a4.z,0.f); a4.w=fmaxf(a4.w,0.f);
    a5.x=fmaxf(a5.x,0.f); a5.y=fmaxf(a5.y,0.f); a5.z=fmaxf(a5.z,0.f); a5.w=fmaxf(a5.w,0.f);
  }
  *(float4*)d0 = a0; *(float4*)d1 = a1; *(float4*)d2 = a2;
  *(float4*)d3 = a3; *(float4*)d4 = a4; *(float4*)d5 = a5;
}

// vector-path matvec, 4 outputs per call
template<int NI, bool GATEF>
__device__ __forceinline__ void vtask(const float* vsrc, const float* wbase, int wstride, float* vdst)
{
  DECL12
#pragma unroll 4
  for (int h = 0; h < NI; h++) {
    float v0 = vsrc[3*h], v1 = vsrc[3*h+1], v2 = vsrc[3*h+2];
    float4 w = *(const float4*)(wbase + h * wstride);
    FMA3x4(v0, v1, v2, w)
  }
  if (GATEF) {
    GATE3(a00,a01,a02, vdst[0],vdst[1],vdst[2])
    GATE3(a10,a11,a12, vdst[3],vdst[4],vdst[5])
    GATE3(a20,a21,a22, vdst[6],vdst[7],vdst[8])
    GATE3(a30,a31,a32, vdst[9],vdst[10],vdst[11])
  } else {
    vdst[0]=a00; vdst[1]=a01; vdst[2]=a02;  vdst[3]=a10; vdst[4]=a11; vdst[5]=a12;
    vdst[6]=a20; vdst[7]=a21; vdst[8]=a22;  vdst[9]=a30; vdst[10]=a31; vdst[11]=a32;
  }
}

// vh matvec: writes vh vectors + vector norms
template<int NI>
__device__ __forceinline__ void vhtask(const float* vsrc, const float* wbase, int wstride,
                                       float* vdst, float* vndst)
{
  DECL12
#pragma unroll 4
  for (int h = 0; h < NI; h++) {
    float v0 = vsrc[3*h], v1 = vsrc[3*h+1], v2 = vsrc[3*h+2];
    float4 w = *(const float4*)(wbase + h * wstride);
    FMA3x4(v0, v1, v2, w)
  }
  vdst[0]=a00; vdst[1]=a01; vdst[2]=a02;  vdst[3]=a10; vdst[4]=a11; vdst[5]=a12;
  vdst[6]=a20; vdst[7]=a21; vdst[8]=a22;  vdst[9]=a30; vdst[10]=a31; vdst[11]=a32;
  vndst[0] = sqrtf(a00*a00+a01*a01+a02*a02 + 1e-8f);
  vndst[1] = sqrtf(a10*a10+a11*a11+a12*a12 + 1e-8f);
  vndst[2] = sqrtf(a20*a20+a21*a21+a22*a22 + 1e-8f);
  vndst[3] = sqrtf(a30*a30+a31*a31+a32*a32 + 1e-8f);
}

__global__ __launch_bounds__(256, 3)
void mpnn_fused(const float* __restrict__ h_V, const float* __restrict__ h_M,
                const int* __restrict__ mask_V, const int* __restrict__ mask_attend,
                const float* __restrict__ Wh1, const float* __restrict__ Wv1,
                const float* __restrict__ Ws1, const float* __restrict__ bs1,
                const float* __restrict__ Wh2, const float* __restrict__ Wv2,
                const float* __restrict__ Ws2, const float* __restrict__ bs2,
                const float* __restrict__ Wh3, const float* __restrict__ Wv3,
                const float* __restrict__ Ws3, const float* __restrict__ bs3,
                const float* __restrict__ Wh4, const float* __restrict__ Wv4,
                const float* __restrict__ Ws4, const float* __restrict__ bs4,
                const float* __restrict__ Wh5, const float* __restrict__ Wv5,
                const float* __restrict__ Ws5, const float* __restrict__ bs5,
                const float* __restrict__ ln0_g, const float* __restrict__ ln0_b,
                const float* __restrict__ ln1_g, const float* __restrict__ ln1_b,
                float* __restrict__ out)
{
  __shared__ __align__(16) float sv[152];     // node features
  __shared__ __align__(16) float dh[F];
  __shared__ __align__(16) float sA[KK][132]; // [0..99]=sM, [100..131]=vn1; later s2 + vn3; node scratch
  __shared__ __align__(16) float sB[KK][116]; // s1 + vn2; later s3
  __shared__ __align__(16) float vA[KK][49];  // 16 vectors x3 (pad): vM, then v1, v2, v3
  __shared__ __align__(16) float vB[KK][99];  // 32 vectors x3 (pad): vh buffers
  __shared__ __align__(16) float s1base[100]; // k-independent part of s1 (incl bias)
  __shared__ float mka[KK];

  const int tid = threadIdx.x;
  const int node = blockIdx.x;

  // ---- P0: stage node feats + edge feats ----
  for (int f = tid; f < F; f += 256) sv[f] = h_V[(long)node * F + f];
  if (tid < KK) mka[tid] = (float)mask_attend[node * KK + tid];
  for (int task = tid; task < KK * 37; task += 256) {
    int k = task / 37, q = task % 37;
    float4 d = *(const float4*)(h_M + ((long)node * KK + k) * F + q * 4);
    float vals[4] = {d.x, d.y, d.z, d.w};
#pragma unroll
    for (int u = 0; u < 4; u++) {
      int f = q * 4 + u;
      if (f < 48) vA[k][f] = vals[u];      // vM: index 3*i+c == f
      else        sA[k][f - 48] = vals[u]; // sM
    }
  }
  __syncthreads();

  // ---- P1: vh1 (per-k, 8 h-outputs/task) || s1base (k-independent sV part) ----
  if (tid < 120) {
    int k = tid >> 2, h0 = (tid & 3) * 8;
    float acc[8][3] = {};
#pragma unroll 4
    for (int i = 0; i < 16; i++) {  // vV rows (from node feats, broadcast)
      float v0 = sv[3*i], v1 = sv[3*i+1], v2 = sv[3*i+2];
      float4 wa = *(const float4*)(Wh1 + i * 32 + h0);
      float4 wb = *(const float4*)(Wh1 + i * 32 + h0 + 4);
      float wv[8] = {wa.x, wa.y, wa.z, wa.w, wb.x, wb.y, wb.z, wb.w};
#pragma unroll
      for (int h = 0; h < 8; h++) {
        acc[h][0] = fmaf(v0, wv[h], acc[h][0]);
        acc[h][1] = fmaf(v1, wv[h], acc[h][1]);
        acc[h][2] = fmaf(v2, wv[h], acc[h][2]);
      }
    }
#pragma unroll 4
    for (int i = 0; i < 16; i++) {  // vM rows
      float v0 = vA[k][3*i], v1 = vA[k][3*i+1], v2 = vA[k][3*i+2];
      float4 wa = *(const float4*)(Wh1 + (16 + i) * 32 + h0);
      float4 wb = *(const float4*)(Wh1 + (16 + i) * 32 + h0 + 4);
      float wv[8] = {wa.x, wa.y, wa.z, wa.w, wb.x, wb.y, wb.z, wb.w};
#pragma unroll
      for (int h = 0; h < 8; h++) {
        acc[h][0] = fmaf(v0, wv[h], acc[h][0]);
        acc[h][1] = fmaf(v1, wv[h], acc[h][1]);
        acc[h][2] = fmaf(v2, wv[h], acc[h][2]);
      }
    }
#pragma unroll
    for (int h = 0; h < 8; h++) {
      vB[k][3*(h0+h)+0] = acc[h][0]; vB[k][3*(h0+h)+1] = acc[h][1]; vB[k][3*(h0+h)+2] = acc[h][2];
      sA[k][100 + h0 + h] = sqrtf(acc[h][0]*acc[h][0] + acc[h][1]*acc[h][1] + acc[h][2]*acc[h][2] + 1e-8f);
    }
  } else if (tid >= 128 && tid < 153) {
    int j0 = (tid - 128) * 4;
    float4 acc = *(const float4*)(bs1 + j0);
    for (int i = 0; i < 100; i++) {
      float s = sv[48 + i];
      float4 w4 = *(const float4*)(Ws1 + i * 100 + j0);
      acc.x = fmaf(s, w4.x, acc.x); acc.y = fmaf(s, w4.y, acc.y);
      acc.z = fmaf(s, w4.z, acc.z); acc.w = fmaf(s, w4.w, acc.w);
    }
    *(float4*)&s1base[j0] = acc;
  }
  __syncthreads();

  // ---- P2: s1 (ktile=6) || v1 ----
  if (tid < 125) {
    int kg = tid / 25, jq = tid % 25, j0 = jq * 4, kb = kg * 6;
    float4 base = *(const float4*)&s1base[j0];
    stask6<true>(Ws1 + 100 * 100 + j0, base, 132,
                 &sA[kb+0][0], &sA[kb+1][0], &sA[kb+2][0], &sA[kb+3][0], &sA[kb+4][0], &sA[kb+5][0],
                 &sB[kb+0][j0], &sB[kb+1][j0], &sB[kb+2][j0], &sB[kb+3][j0], &sB[kb+4][j0], &sB[kb+5][j0]);
  } else if (tid >= 128 && tid < 248) {
    int vt = tid - 128, k = vt >> 2, o0 = (vt & 3) * 4;
    vtask<32, true>(&vB[k][0], Wv1 + o0, 16, &vA[k][3 * o0]);
  }
  __syncthreads();

  // ---- P3: vh2 ----
  if (tid < 120) {
    int k = tid >> 2, h0 = (tid & 3) * 4;
    vhtask<16>(&vA[k][0], Wh2 + h0, 16, &vB[k][3 * h0], &sB[k][100 + h0]);
  }
  __syncthreads();

  // ---- P4: s2 (ktile=6) || v2 ----
  if (tid < 125) {
    int kg = tid / 25, jq = tid % 25, j0 = jq * 4, kb = kg * 6;
    float4 base = *(const float4*)(bs2 + j0);
    stask6<true>(Ws2 + j0, base, 116,
                 &sB[kb+0][0], &sB[kb+1][0], &sB[kb+2][0], &sB[kb+3][0], &sB[kb+4][0], &sB[kb+5][0],
                 &sA[kb+0][j0], &sA[kb+1][j0], &sA[kb+2][j0], &sA[kb+3][j0], &sA[kb+4][j0], &sA[kb+5][j0]);
  } else if (tid >= 128 && tid < 248) {
    int vt = tid - 128, k = vt >> 2, o0 = (vt & 3) * 4;
    vtask<16, true>(&vB[k][0], Wv2 + o0, 16, &vA[k][3 * o0]);
  }
  __syncthreads();

  // ---- P5: vh3 ----
  if (tid < 120) {
    int k = tid >> 2, h0 = (tid & 3) * 4;
    vhtask<16>(&vA[k][0], Wh3 + h0, 16, &vB[k][3 * h0], &sA[k][100 + h0]);
  }
  __syncthreads();

  // ---- P6: s3 (ktile=6, no relu) || v3 (no gate) ----
  if (tid < 125) {
    int kg = tid / 25, jq = tid % 25, j0 = jq * 4, kb = kg * 6;
    float4 base = *(const float4*)(bs3 + j0);
    stask6<false>(Ws3 + j0, base, 116,
                  &sA[kb+0][0], &sA[kb+1][0], &sA[kb+2][0], &sA[kb+3][0], &sA[kb+4][0], &sA[kb+5][0],
                  &sB[kb+0][j0], &sB[kb+1][j0], &sB[kb+2][j0], &sB[kb+3][j0], &sB[kb+4][j0], &sB[kb+5][j0]);
  } else if (tid >= 128 && tid < 248) {
    int vt = tid - 128, k = vt >> 2, o0 = (vt & 3) * 4;
    vtask<16, false>(&vB[k][0], Wv3 + o0, 16, &vA[k][3 * o0]);
  }
  __syncthreads();

  // ---- P7: masked mean over K ----
  for (int f = tid; f < F; f += 256) {
    float acc = 0.f;
    if (f < 48) { for (int k = 0; k < KK; k++) acc += mka[k] * vA[k][f]; }
    else        { int j = f - 48; for (int k = 0; k < KK; k++) acc += mka[k] * sB[k][j]; }
    dh[f] = acc * (1.f / (float)KK);
  }
  __syncthreads();

  // ---- node phase (scratch in sA) ----
  float* ns   = &sA[0][0];
  float* xb   = ns;          // 148
  float* hb   = ns + 160;    // 148
  float* nvh4 = ns + 320;    // 96
  float* nvn4 = ns + 416;    // 32
  float* s4   = ns + 448;    // 400 (+32 vn5 at 848 -> contiguous 432)
  float* nvn5 = ns + 848;    // 32
  float* v4   = ns + 880;    // 96
  float* nvh5 = ns + 976;    // 96
  float* v5   = ns + 1072;   // 48
  float* s5   = ns + 1120;   // 100
  float* red  = ns + 1220;   // 4
  float* part = ns + 1232;   // 400

  for (int f = tid; f < F; f += 256) xb[f] = sv[f] + dh[f];
  __syncthreads();
  // ln0 stats via wave shuffles
  if (tid < 64) {
    float a = (tid < 50) ? xb[48 + 2 * tid] : 0.f;
    float b = (tid < 50) ? xb[48 + 2 * tid + 1] : 0.f;
    float s = a + b, q = a * a + b * b;
    for (int off = 32; off; off >>= 1) { s += __shfl_down(s, off); q += __shfl_down(q, off); }
    if (tid == 0) { red[1] = s * 0.01f; red[2] = q * 0.01f; }
  } else if (tid < 128) {
    int l = tid - 64;
    float v = (l < 48) ? xb[l] : 0.f;
    float q = v * v;
    for (int off = 32; off; off >>= 1) q += __shfl_down(q, off);
    if (l == 0) red[0] = sqrtf(q * (1.f / 16.f) + 1e-8f);
  }
  __syncthreads();
  {
    float denom = red[0], mu = red[1];
    float var = red[2] - mu * mu;
    float rs = rsqrtf(var + 1e-5f);
    for (int f = tid; f < F; f += 256) {
      if (f < 48) hb[f] = xb[f] / denom;
      else { int j = f - 48; hb[f] = (xb[f] - mu) * rs * ln0_g[j] + ln0_b[j]; }
    }
  }
  __syncthreads();

  // GVP4: vh4 (16 -> 32)
  if (tid < 8) {
    int h0 = tid * 4;
    vhtask<16>(hb, Wh4 + h0, 32, &nvh4[3 * h0], &nvn4[h0]);
  }
  __syncthreads();
  // s_out4 (400 outs, dot 132, relu) || v4 (gated)
  if (tid < 100) {
    int j0 = tid * 4;
    float4 acc = *(const float4*)(bs4 + j0);
    const float* w = Ws4 + j0;
#pragma unroll 4
    for (int i = 0; i < 100; i++) {
      float s = hb[48 + i];
      float4 w4 = *(const float4*)(w + i * 400);
      acc.x = fmaf(s, w4.x, acc.x); acc.y = fmaf(s, w4.y, acc.y);
      acc.z = fmaf(s, w4.z, acc.z); acc.w = fmaf(s, w4.w, acc.w);
    }
#pragma unroll 4
    for (int h = 0; h < 32; h++) {
      float s = nvn4[h];
      float4 w4 = *(const float4*)(w + (100 + h) * 400);
      acc.x = fmaf(s, w4.x, acc.x); acc.y = fmaf(s, w4.y, acc.y);
      acc.z = fmaf(s, w4.z, acc.z); acc.w = fmaf(s, w4.w, acc.w);
    }
    acc.x = fmaxf(acc.x, 0.f); acc.y = fmaxf(acc.y, 0.f);
    acc.z = fmaxf(acc.z, 0.f); acc.w = fmaxf(acc.w, 0.f);
    *(float4*)&s4[j0] = acc;
  } else if (tid >= 128 && tid < 136) {
    int o0 = (tid - 128) * 4;
    vtask<32, true>(nvh4, Wv4 + o0, 32, &v4[3 * o0]);
  }
  __syncthreads();
  // GVP5: vh5 (32 -> 32)
  if (tid < 8) {
    int h0 = tid * 4;
    vhtask<32>(v4, Wh5 + h0, 32, &nvh5[3 * h0], &nvn5[h0]);
  }
  __syncthreads();
  // s_out5 partials (dot 432 split 4 ways) || v5 (no gate)
  if (tid < 100) {
    int jq = tid / 4, c = tid % 4, j0 = jq * 4;
    int ibeg = c * 108, iend = ibeg + 108;
    float4 acc = make_float4(0.f, 0.f, 0.f, 0.f);
    const float* w = Ws5 + j0;
#pragma unroll 4
    for (int i = ibeg; i < iend; i++) {
      float s = s4[i];  // s4[0..399] then nvn5[0..31], contiguous
      float4 w4 = *(const float4*)(w + i * 100);
      acc.x = fmaf(s, w4.x, acc.x); acc.y = fmaf(s, w4.y, acc.y);
      acc.z = fmaf(s, w4.z, acc.z); acc.w = fmaf(s, w4.w, acc.w);
    }
    *(float4*)&part[tid * 4] = acc;
  } else if (tid >= 128 && tid < 132) {
    int o0 = (tid - 128) * 4;
    vtask<32, false>(nvh5, Wv5 + o0, 16, &v5[3 * o0]);
  }
  __syncthreads();
  if (tid < 25) {
    int j0 = tid * 4;
    float4 p0 = *(const float4*)&part[(tid * 4 + 0) * 4];
    float4 p1 = *(const float4*)&part[(tid * 4 + 1) * 4];
    float4 p2 = *(const float4*)&part[(tid * 4 + 2) * 4];
    float4 p3 = *(const float4*)&part[(tid * 4 + 3) * 4];
    float4 b = *(const float4*)(bs5 + j0);
    s5[j0 + 0] = b.x + p0.x + p1.x + p2.x + p3.x;
    s5[j0 + 1] = b.y + p0.y + p1.y + p2.y + p3.y;
    s5[j0 + 2] = b.z + p0.z + p1.z + p2.z + p3.z;
    s5[j0 + 3] = b.w + p0.w + p1.w + p2.w + p3.w;
  }
  __syncthreads();
  // x2 = h + dh2
  for (int f = tid; f < F; f += 256) {
    float d = (f < 48) ? v5[f] : s5[f - 48];
    xb[f] = hb[f] + d;
  }
  __syncthreads();
  // ln1 stats
  if (tid < 64) {
    float a = (tid < 50) ? xb[48 + 2 * tid] : 0.f;
    float b = (tid < 50) ? xb[48 + 2 * tid + 1] : 0.f;
    float s = a + b, q = a * a + b * b;
    for (int off = 32; off; off >>= 1) { s += __shfl_down(s, off); q += __shfl_down(q, off); }
    if (tid == 0) { red[1] = s * 0.01f; red[2] = q * 0.01f; }
  } else if (tid < 128) {
    int l = tid - 64;
    float v = (l < 48) ? xb[l] : 0.f;
    float q = v * v;
    for (int off = 32; off; off >>= 1) q += __shfl_down(q, off);
    if (l == 0) red[0] = sqrtf(q * (1.f / 16.f) + 1e-8f);
  }
  __syncthreads();
  {
    float denom = red[0], mu = red[1];
    float var = red[2] - mu * mu;
    float rs = rsqrtf(var + 1e-5f);
    float mv = (float)mask_V[node];
    for (int f = tid; f < F; f += 256) {
      float val;
      if (f < 48) val = xb[f] / denom;
      else { int j = f - 48; val = (xb[f] - mu) * rs * ln1_g[j] + ln1_b[j]; }
      out[(long)node * F + f] = mv * val;
    }
  }
}

extern "C" void kernel_launch(void* const* d_in, const int* in_sizes, int n_in,
                              void* d_out, int out_size, void* d_ws, size_t ws_size,
                              hipStream_t stream) {
  const float* h_V  = (const float*)d_in[0];
  const float* h_M  = (const float*)d_in[1];
  const int* mask_V = (const int*)d_in[2];
  const int* mask_attend = (const int*)d_in[3];
  const float* Wh1 = (const float*)d_in[4];
  const float* Wv1 = (const float*)d_in[5];
  const float* Ws1 = (const float*)d_in[6];
  const float* bs1 = (const float*)d_in[7];
  const float* Wh2 = (const float*)d_in[8];
  const float* Wv2 = (const float*)d_in[9];
  const float* Ws2 = (const float*)d_in[10];
  const float* bs2 = (const float*)d_in[11];
  const float* Wh3 = (const float*)d_in[12];
  const float* Wv3 = (const float*)d_in[13];
  const float* Ws3 = (const float*)d_in[14];
  const float* bs3 = (const float*)d_in[15];
  const float* Wh4 = (const float*)d_in[16];
  const float* Wv4 = (const float*)d_in[17];
  const float* Ws4 = (const float*)d_in[18];
  const float* bs4 = (const float*)d_in[19];
  const float* Wh5 = (const float*)d_in[20];
  const float* Wv5 = (const float*)d_in[21];
  const float* Ws5 = (const float*)d_in[22];
  const float* bs5 = (const float*)d_in[23];
  const float* ln0_g = (const float*)d_in[24];
  const float* ln0_b = (const float*)d_in[25];
  const float* ln1_g = (const float*)d_in[26];
  const float* ln1_b = (const float*)d_in[27];
  float* out = (float*)d_out;

  mpnn_fused<<<dim3(NNODE), dim3(256), 0, stream>>>(
      h_V, h_M, mask_V, mask_attend,
      Wh1, Wv1, Ws1, bs1, Wh2, Wv2, Ws2, bs2, Wh3, Wv3, Ws3, bs3,
      Wh4, Wv4, Ws4, bs4, Wh5, Wv5, Ws5, bs5,
      ln0_g, ln0_b, ln1_g, ln1_b, out);
}